// Round 5
// baseline (495.474 us; speedup 1.0000x reference)
//
#include <hip/hip_runtime.h>
#include <math.h>

#define BATCH 64
#define CDX 256
#define NXX 784
#define TRIU_N 32896
#define MSZ 65536            // elems per swizzled 256x256 matrix
// LDS staging geometry (ushort elems)
#define QS 2080              // k8-region stride: 256 rows * 8 + 32 pad
#define ASX (4*QS)           // per-array stride (4 k8-regions per 32k stage)
#define BUFL (4*ASX)         // per-buffer: 4 arrays (Ahi,Alo,Bhi,Blo)
#define SMEM_BYTES (2*BUFL*2)   // 133120 B (also holds 128x257 fp32 bounce)

typedef unsigned short ushort_t;
typedef unsigned int uint_t;
typedef __attribute__((ext_vector_type(8))) short short8;
typedef __attribute__((ext_vector_type(8))) unsigned short ushort8;
typedef __attribute__((ext_vector_type(16))) float floatx16;

__device__ __forceinline__ ushort_t f2bf(float x) {
    uint_t u = __float_as_uint(x);
    u += 0x7fffu + ((u >> 16) & 1u);
    return (ushort_t)(u >> 16);
}
__device__ __forceinline__ float bf2f(ushort_t h) {
    return __uint_as_float(((uint_t)h) << 16);
}
__device__ __forceinline__ void split2(float x, ushort_t& h, ushort_t& l) {
    h = f2bf(x);
    l = f2bf(x - bf2f(h));
}

// global swizzled layout of a 256x256 matrix: elem (r,c) at (c>>3)*2048 + r*8 + (c&7)
// => one BK=32 k-stage is a contiguous 8192-elem region; staging is pure
//    contiguous global_load_lds chunks.

// ---------------------------------------------------------------------------
// One BK=32 MFMA stage: wave computes quadrants (rowq+{0,32}) x (colq+{0,32}).
// 16 ds_read_b128 + 24 MFMA per wave.
__device__ __forceinline__ void mfma_stage(const ushort_t* base, int bOff,
                                           int rowq, int colq, int khalf, int lrow,
                                           floatx16 acc[2][2]) {
    #pragma unroll
    for (int ks = 0; ks < 2; ++ks) {
        const int q = ks * 2 + khalf;
        const ushort_t* ab = base + q * QS + lrow * 8;
        short8 aH[2], aL[2];
        #pragma unroll
        for (int rt = 0; rt < 2; ++rt) {
            aH[rt] = *(const short8*)(ab + (rowq + rt * 32) * 8);
            aL[rt] = *(const short8*)(ab + ASX + (rowq + rt * 32) * 8);
        }
        #pragma unroll
        for (int cq = 0; cq < 2; ++cq) {
            short8 bH = *(const short8*)(ab + bOff + (colq + cq * 32) * 8);
            short8 bL = *(const short8*)(ab + bOff + ASX + (colq + cq * 32) * 8);
            #pragma unroll
            for (int rt = 0; rt < 2; ++rt) {
                acc[rt][cq] = __builtin_amdgcn_mfma_f32_32x32x16_bf16(aH[rt], bH, acc[rt][cq], 0, 0, 0);
                acc[rt][cq] = __builtin_amdgcn_mfma_f32_32x32x16_bf16(aH[rt], bL, acc[rt][cq], 0, 0, 0);
                acc[rt][cq] = __builtin_amdgcn_mfma_f32_32x32x16_bf16(aL[rt], bH, acc[rt][cq], 0, 0, 0);
            }
        }
    }
}

// ---------------------------------------------------------------------------
__device__ __forceinline__ void gll(const ushort_t* src, ushort_t* dst) {
    __builtin_amdgcn_global_load_lds(
        (const __attribute__((address_space(1))) unsigned int*)src,
        (__attribute__((address_space(3))) unsigned int*)dst, 16, 0, 0);
}

// stage one BK=32 chunk of operands (swizzled global) into LDS buffer `buf`.
__device__ __forceinline__ void stage_ns(const ushort_t* Ah, const ushort_t* Al,
                                         const ushort_t* Bh, const ushort_t* Bl,
                                         bool same, ushort_t* lds, int buf,
                                         int wv, int lane, int s) {
    ushort_t* dstb = lds + buf * BUFL;
    if (same) {
        #pragma unroll
        for (int j = 0; j < 2; ++j) {
            int ck = wv * 2 + j;
            int arr = ck >> 4, i = ck & 15;
            const ushort_t* src = (arr ? Al : Ah) + s * 8192 + i * 512 + lane * 8;
            gll(src, dstb + arr * ASX + (i >> 2) * QS + (i & 3) * 512);
        }
    } else {
        #pragma unroll
        for (int j = 0; j < 4; ++j) {
            int ck = wv * 4 + j;
            int arr = ck >> 4, i = ck & 15;
            const ushort_t* sp = (arr == 0) ? Ah : (arr == 1) ? Al : (arr == 2) ? Bh : Bl;
            gll(sp + s * 8192 + i * 512 + lane * 8,
                dstb + arr * ASX + (i >> 2) * QS + (i & 3) * 512);
        }
    }
}

// ---------------------------------------------------------------------------
// One NS GEMM: acc = A.B^T (symmetric operands => NT).  Epilogues:
// MODE 0: O = 1.5*M - 0.5*acc          (split2 store)
// MODE 1: O = it*(1.5*M - 0.5*it*acc)  (iter1: trace scale folded)
// MODE 2: out_triu = st*(1.5*M - 0.5*acc)
template<int MODE>
__device__ void ns_gemm(ushort_t* lds, float* fs, bool same,
                        const ushort_t* Ah, const ushort_t* Al,
                        const ushort_t* Bh, const ushort_t* Bl,
                        const ushort_t* Mh, const ushort_t* Ml,
                        ushort_t* Oh, ushort_t* Ol, float* outT,
                        float it, float st,
                        int tid, int lane, int wv, int khalf, int lrow,
                        int rowq, int colq) {
    __threadfence();        // drain my stores + invalidate L1 (buffer-reuse safety)
    __syncthreads();

    floatx16 acc[2][2];
    #pragma unroll
    for (int a = 0; a < 2; ++a)
        #pragma unroll
        for (int b = 0; b < 2; ++b)
            #pragma unroll
            for (int i = 0; i < 16; ++i) acc[a][b][i] = 0.f;

    const int bOff = same ? 0 : 2 * ASX;
    stage_ns(Ah, Al, Bh, Bl, same, lds, 0, wv, lane, 0);
    #pragma unroll 2
    for (int s = 0; s < 8; ++s) {
        __syncthreads();
        if (s < 7) stage_ns(Ah, Al, Bh, Bl, same, lds, (s + 1) & 1, wv, lane, s + 1);
        mfma_stage(lds + (s & 1) * BUFL, bOff, rowq, colq, khalf, lrow, acc);
    }

    // epilogue: two 128-row bounce passes through LDS (fp32, stride 257)
    #pragma unroll
    for (int p = 0; p < 2; ++p) {
        __syncthreads();
        if ((wv >> 3) == p) {
            int rbase = ((wv >> 2) & 1) * 64;
            #pragma unroll
            for (int rt = 0; rt < 2; ++rt)
                #pragma unroll
                for (int cq = 0; cq < 2; ++cq)
                    #pragma unroll
                    for (int i = 0; i < 16; ++i) {
                        int rr = rbase + rt * 32 + (i & 3) + ((i >> 2) << 3) + (khalf << 2);
                        fs[rr * 257 + colq + cq * 32 + lrow] = acc[rt][cq][i];
                    }
        }
        __syncthreads();
        const int rl = tid & 127, g = tid >> 7;
        const int r = p * 128 + rl;
        #pragma unroll
        for (int ii = 0; ii < 4; ++ii) {
            int c0 = g * 8 + ii * 64;
            int so = (c0 >> 3) * 2048 + r * 8;
            float v[8];
            #pragma unroll
            for (int j = 0; j < 8; ++j) v[j] = fs[rl * 257 + c0 + j];
            ushort8 mh = *(const ushort8*)(Mh + so);
            ushort8 ml = *(const ushort8*)(Ml + so);
            if (MODE == 2) {
                int tb = r * CDX - (r * (r - 1)) / 2 - r;
                #pragma unroll
                for (int j = 0; j < 8; ++j) {
                    float m = bf2f(mh[j]) + bf2f(ml[j]);
                    float y = fmaf(1.5f, m, -0.5f * v[j]);
                    int c = c0 + j;
                    if (c >= r) outT[tb + c] = st * y;
                }
            } else {
                ushort8 hh, ll;
                #pragma unroll
                for (int j = 0; j < 8; ++j) {
                    float m = bf2f(mh[j]) + bf2f(ml[j]);
                    float y;
                    if (MODE == 1) y = it * fmaf(1.5f, m, -0.5f * it * v[j]);
                    else           y = fmaf(1.5f, m, -0.5f * v[j]);
                    ushort_t h, l; split2(y, h, l);
                    hh[j] = h; ll[j] = l;
                }
                *(ushort8*)(Oh + so) = hh;
                *(ushort8*)(Ol + so) = ll;
            }
        }
    }
}

// ---------------------------------------------------------------------------
// One block per batch item: Gram (+means+trace) then the 6-GEMM NS chain.
__global__ __launch_bounds__(1024, 1)
void covns_k(const float* __restrict__ X,
             ushort_t* B0h, ushort_t* B0l, ushort_t* B1h, ushort_t* B1l,
             ushort_t* B2h, ushort_t* B2l, ushort_t* B3h, ushort_t* B3l,
             float* __restrict__ out) {
    __shared__ __align__(16) char smem[SMEM_BYTES];
    __shared__ float smean[256];
    __shared__ float sred[16];
    __shared__ float s_tr[2];
    ushort_t* lds = (ushort_t*)smem;
    float* fs = (float*)smem;

    const int bbx = blockIdx.x;
    const int tid = threadIdx.x, lane = tid & 63, wv = tid >> 6;
    const int khalf = lane >> 5, lrow = lane & 31;
    const int rowq = (wv >> 2) * 64, colq = (wv & 3) * 64;
    const size_t mb = (size_t)bbx * MSZ;
    const float* Xb = X + (size_t)bbx * CDX * NXX;

    // ---------------- Phase 1: Gram (X X^T), means, trace ----------------
    floatx16 acc[2][2];
    #pragma unroll
    for (int a = 0; a < 2; ++a)
        #pragma unroll
        for (int b = 0; b < 2; ++b)
            #pragma unroll
            for (int i = 0; i < 16; ++i) acc[a][b][i] = 0.f;

    const int grow = tid >> 2, gkq = tid & 3;
    float msum = 0.f;
    float4 cur[2][2];   // [parity][half of 8 floats]

    auto loadst = [&](int s, int d) {
        int gk = s * 32 + gkq * 8;
        if (gk < NXX) {
            const float* p = Xb + (size_t)grow * NXX + gk;
            cur[d][0] = *(const float4*)p;
            cur[d][1] = *(const float4*)(p + 4);
        } else {
            float4 z = make_float4(0.f, 0.f, 0.f, 0.f);
            cur[d][0] = z; cur[d][1] = z;
        }
    };
    auto splitwr = [&](int d) {
        float f[8] = {cur[d][0].x, cur[d][0].y, cur[d][0].z, cur[d][0].w,
                      cur[d][1].x, cur[d][1].y, cur[d][1].z, cur[d][1].w};
        msum += ((f[0] + f[1]) + (f[2] + f[3])) + ((f[4] + f[5]) + (f[6] + f[7]));
        uint_t hp[4], lp[4];
        #pragma unroll
        for (int i = 0; i < 4; ++i) {
            ushort_t h0, l0, h1, l1;
            split2(f[2 * i], h0, l0); split2(f[2 * i + 1], h1, l1);
            hp[i] = (uint_t)h0 | ((uint_t)h1 << 16);
            lp[i] = (uint_t)l0 | ((uint_t)l1 << 16);
        }
        ushort_t* dst = lds + d * BUFL + gkq * QS + grow * 8;
        *(uint4*)dst         = make_uint4(hp[0], hp[1], hp[2], hp[3]);
        *(uint4*)(dst + ASX) = make_uint4(lp[0], lp[1], lp[2], lp[3]);
    };
    auto gram_iter = [&](int s, int par) {
        __syncthreads();
        if (s + 2 <= 24) loadst(s + 2, par);
        if (s + 1 <= 24) splitwr(par ^ 1);
        mfma_stage(lds + par * BUFL, 0, rowq, colq, khalf, lrow, acc);
    };

    loadst(0, 0);
    splitwr(0);
    loadst(1, 1);
    for (int s = 0; s < 24; s += 2) { gram_iter(s, 0); gram_iter(s + 1, 1); }
    gram_iter(24, 0);

    // means reduce
    __syncthreads();
    fs[tid] = msum;
    __syncthreads();
    if (tid < 256)
        smean[tid] = (fs[tid * 4] + fs[tid * 4 + 1] + fs[tid * 4 + 2] + fs[tid * 4 + 3]) * (1.0f / NXX);

    // Sigma epilogue (bounce) + trace partials
    float tsum = 0.f;
    #pragma unroll
    for (int p = 0; p < 2; ++p) {
        __syncthreads();
        if ((wv >> 3) == p) {
            int rbase = ((wv >> 2) & 1) * 64;
            #pragma unroll
            for (int rt = 0; rt < 2; ++rt)
                #pragma unroll
                for (int cq = 0; cq < 2; ++cq)
                    #pragma unroll
                    for (int i = 0; i < 16; ++i) {
                        int rr = rbase + rt * 32 + (i & 3) + ((i >> 2) << 3) + (khalf << 2);
                        fs[rr * 257 + colq + cq * 32 + lrow] = acc[rt][cq][i];
                    }
        }
        __syncthreads();
        const int rl = tid & 127, g = tid >> 7;
        const int r = p * 128 + rl;
        const float mr = smean[r];
        #pragma unroll
        for (int ii = 0; ii < 4; ++ii) {
            int c0 = g * 8 + ii * 64;
            int so = (c0 >> 3) * 2048 + r * 8;
            ushort8 hh, ll;
            #pragma unroll
            for (int j = 0; j < 8; ++j) {
                float sig = fs[rl * 257 + c0 + j] * (1.0f / NXX) - mr * smean[c0 + j];
                if (c0 + j == r) tsum += sig;
                ushort_t h, l; split2(sig, h, l);
                hh[j] = h; ll[j] = l;
            }
            *(ushort8*)(B0h + mb + so) = hh;
            *(ushort8*)(B0l + mb + so) = ll;
        }
    }
    // trace reduce (block-local)
    for (int off = 32; off; off >>= 1) tsum += __shfl_down(tsum, off, 64);
    if (lane == 0) sred[wv] = tsum;
    __syncthreads();
    if (tid == 0) {
        float t = 0.f;
        #pragma unroll
        for (int i = 0; i < 16; ++i) t += sred[i];
        s_tr[0] = 1.0f / t;
        s_tr[1] = sqrtf(t);
    }
    __syncthreads();
    const float it = s_tr[0], st = s_tr[1];

    // ---------------- Phase 2: 6-GEMM Newton-Schulz chain ----------------
    // Y1 = it*(1.5*Sig - 0.5*it*Sig^2)            [B0 -> B1]
    ns_gemm<1>(lds, fs, true,  B0h + mb, B0l + mb, B0h + mb, B0l + mb,
               B0h + mb, B0l + mb, B1h + mb, B1l + mb, nullptr,
               it, 0.f, tid, lane, wv, khalf, lrow, rowq, colq);
    // T1 = 1.5*Y1 - 0.5*Y1^2                      [B1 -> B2]
    ns_gemm<0>(lds, fs, true,  B1h + mb, B1l + mb, B1h + mb, B1l + mb,
               B1h + mb, B1l + mb, B2h + mb, B2l + mb, nullptr,
               0.f, 0.f, tid, lane, wv, khalf, lrow, rowq, colq);
    // Y2 = 1.5*Y1 - 0.5*(Y1*T1)                   [B1,B2 -> B3]
    ns_gemm<0>(lds, fs, false, B1h + mb, B1l + mb, B2h + mb, B2l + mb,
               B1h + mb, B1l + mb, B3h + mb, B3l + mb, nullptr,
               0.f, 0.f, tid, lane, wv, khalf, lrow, rowq, colq);
    // T2 = 1.5*Y2 - 0.5*(Y1*Y2)                   [B1,B3 -> B0]
    ns_gemm<0>(lds, fs, false, B1h + mb, B1l + mb, B3h + mb, B3l + mb,
               B3h + mb, B3l + mb, B0h + mb, B0l + mb, nullptr,
               0.f, 0.f, tid, lane, wv, khalf, lrow, rowq, colq);
    // T3 = 1.5*T2 - 0.5*T2^2                      [B0 -> B2]
    ns_gemm<0>(lds, fs, true,  B0h + mb, B0l + mb, B0h + mb, B0l + mb,
               B0h + mb, B0l + mb, B2h + mb, B2l + mb, nullptr,
               0.f, 0.f, tid, lane, wv, khalf, lrow, rowq, colq);
    // out = st*(1.5*Y2 - 0.5*(Y2*T3)), triu       [B3,B2 -> out]
    ns_gemm<2>(lds, fs, false, B3h + mb, B3l + mb, B2h + mb, B2l + mb,
               B3h + mb, B3l + mb, nullptr, nullptr, out + (size_t)bbx * TRIU_N,
               0.f, st, tid, lane, wv, khalf, lrow, rowq, colq);
}

// ---------------------------------------------------------------------------
extern "C" void kernel_launch(void* const* d_in, const int* in_sizes, int n_in,
                              void* d_out, int out_size, void* d_ws, size_t ws_size,
                              hipStream_t stream) {
    const float* x = (const float*)d_in[0];
    float* out = (float*)d_out;
    char* ws = (char*)d_ws;
    const size_t HS = (size_t)BATCH * MSZ * 2;   // 8,388,608 B per array
    ushort_t* B0h = (ushort_t*)(ws + 0 * HS);
    ushort_t* B0l = (ushort_t*)(ws + 1 * HS);
    ushort_t* B1h = (ushort_t*)(ws + 2 * HS);
    ushort_t* B1l = (ushort_t*)(ws + 3 * HS);
    ushort_t* B2h = (ushort_t*)(ws + 4 * HS);
    ushort_t* B2l = (ushort_t*)(ws + 5 * HS);
    ushort_t* B3h = (ushort_t*)(ws + 6 * HS);
    ushort_t* B3l = (ushort_t*)(ws + 7 * HS);
    // total 64 MiB workspace, same footprint as prior rounds

    covns_k<<<BATCH, 1024, 0, stream>>>(x, B0h, B0l, B1h, B1l,
                                        B2h, B2l, B3h, B3l, out);
}

// Round 6
// 299.175 us; speedup vs baseline: 1.6561x; 1.6561x over previous
//
#include <hip/hip_runtime.h>
#include <math.h>

#define BATCH 64
#define CD 256
#define NX 784
#define TRIU_N 32896
#define MSZ 65536           // elems per swizzled 256x256 matrix
#define REG_STRIDE 1032     // 128 rows * 8 elems + 8 pad
#define ARR_STRIDE 4128
#define BUF_STRIDE 16512

typedef unsigned short ushort_t;
typedef unsigned int uint_t;
typedef __attribute__((ext_vector_type(8))) short short8;
typedef __attribute__((ext_vector_type(8))) unsigned short ushort8;
typedef __attribute__((ext_vector_type(16))) float floatx16;

__device__ __forceinline__ ushort_t f2bf(float x) {
    uint_t u = __float_as_uint(x);
    u += 0x7fffu + ((u >> 16) & 1u);
    return (ushort_t)(u >> 16);
}
__device__ __forceinline__ float bf2f(ushort_t h) {
    return __uint_as_float(((uint_t)h) << 16);
}
__device__ __forceinline__ void split2(float x, ushort_t& h, ushort_t& l) {
    h = f2bf(x);
    l = f2bf(x - bf2f(h));
}

// swizzled offset of (r,c) in a 256x256 matrix (dense):
// [p=r>>7][s=c>>5][ks=(c>>4)&1][kh=(c>>3)&1][r&127][c&7]
__device__ __forceinline__ int swoff(int r, int c) {
    int p = r >> 7, s = (c >> 5) & 7, ks = (c >> 4) & 1, kh = (c >> 3) & 1;
    return ((((p * 8 + s) * 2 + ks) * 2 + kh) * 128 + (r & 127)) * 8 + (c & 7);
}

// ---------------------------------------------------------------------------
// One BK=32 stage: wave computes quadrant-row wr (32 rows) x 2 col-quads.
__device__ __forceinline__ void mfma_stage8(const ushort_t* us, int bufbase,
                                            int wr, int wcp, int khalf, int lrow,
                                            floatx16* acc) {
    #pragma unroll
    for (int ks = 0; ks < 2; ++ks) {
        const int rid = ks * 2 + khalf;
        const ushort_t* rb = us + bufbase + rid * REG_STRIDE + lrow * 8;
        short8 aH = *(const short8*)(rb + wr * 256);
        short8 aL = *(const short8*)(rb + ARR_STRIDE + wr * 256);
        #pragma unroll
        for (int cq = 0; cq < 2; ++cq) {
            const int col = wcp * 2 + cq;
            short8 bH = *(const short8*)(rb + 2 * ARR_STRIDE + col * 256);
            short8 bL = *(const short8*)(rb + 3 * ARR_STRIDE + col * 256);
            acc[cq] = __builtin_amdgcn_mfma_f32_32x32x16_bf16(aH, bH, acc[cq], 0, 0, 0);
            acc[cq] = __builtin_amdgcn_mfma_f32_32x32x16_bf16(aH, bL, acc[cq], 0, 0, 0);
            acc[cq] = __builtin_amdgcn_mfma_f32_32x32x16_bf16(aL, bH, acc[cq], 0, 0, 0);
        }
    }
}

__device__ __forceinline__ void ns_prefetch(const ushort_t* const* arrp, ushort_t* us,
                                            int wv, int lane, int s, int buf) {
    #pragma unroll
    for (int j = 0; j < 4; ++j) {
        int ck = wv * 4 + j;
        int arr = ck >> 3, rid = (ck >> 1) & 3, half = ck & 1;
        const ushort_t* g = arrp[arr] + s * 4096 + rid * 1024 + half * 512 + lane * 8;
        ushort_t* l = us + buf * BUF_STRIDE + arr * ARR_STRIDE + rid * REG_STRIDE + half * 512;
        __builtin_amdgcn_global_load_lds(
            (const __attribute__((address_space(1))) unsigned int*)g,
            (__attribute__((address_space(3))) unsigned int*)l, 16, 0, 0);
    }
}

// ---------------------------------------------------------------------------
// per-batch 4-block sync: release my stores to LLC, bump counter, wait all 4,
// invalidate stale caches.
__device__ __forceinline__ void batch_sync(int* cnt, int tgt, int tid) {
    __syncthreads();                    // all waves' stores drained to L2
    if (tid == 0) {
        __threadfence();                // wbl2: L2 -> LLC
        __hip_atomic_fetch_add(cnt, 1, __ATOMIC_RELAXED, __HIP_MEMORY_SCOPE_AGENT);
        while (__hip_atomic_load(cnt, __ATOMIC_RELAXED, __HIP_MEMORY_SCOPE_AGENT) < tgt)
            __builtin_amdgcn_s_sleep(4);
        __threadfence();                // inv: discard stale L1/L2
    }
    __syncthreads();
}

// ---------------------------------------------------------------------------
// One NS GEMM step. MODE 0: O = 1.5*M - 0.5*acc
//                  MODE 1: O = it*(1.5*M - 0.5*it*acc)   (iter1, scale folded)
//                  MODE 2: out_triu = st*(1.5*M - 0.5*acc)
template<int MODE>
__device__ void ns_step(float* fsmem,
                        const ushort_t* __restrict__ Ah, const ushort_t* __restrict__ Al,
                        const ushort_t* __restrict__ Bh, const ushort_t* __restrict__ Bl,
                        const ushort_t* __restrict__ Mh, const ushort_t* __restrict__ Ml,
                        ushort_t* __restrict__ O1h, ushort_t* __restrict__ O1l,
                        float* __restrict__ outT, float it, float st,
                        int rowBase, int colBase, size_t mb, int bbx,
                        int tid, int lane, int wv, int wr, int wcp, int khalf, int lrow) {
    ushort_t* us = (ushort_t*)fsmem;
    const ushort_t* arrp[4] = {
        Ah + mb + (size_t)(rowBase >> 7) * 32768,
        Al + mb + (size_t)(rowBase >> 7) * 32768,
        Bh + mb + (size_t)(colBase >> 7) * 32768,
        Bl + mb + (size_t)(colBase >> 7) * 32768 };

    floatx16 acc[2];
    #pragma unroll
    for (int cq = 0; cq < 2; ++cq)
        #pragma unroll
        for (int i = 0; i < 16; ++i) acc[cq][i] = 0.f;

    ns_prefetch(arrp, us, wv, lane, 0, 0);
    #pragma unroll
    for (int s = 0; s < 8; ++s) {
        __syncthreads();
        if (s < 7) ns_prefetch(arrp, us, wv, lane, s + 1, (s + 1) & 1);
        mfma_stage8(us, (s & 1) * BUF_STRIDE, wr, wcp, khalf, lrow, acc);
    }

    __syncthreads();
    #pragma unroll
    for (int cq = 0; cq < 2; ++cq)
        #pragma unroll
        for (int i = 0; i < 16; ++i) {
            int rl = (i & 3) + ((i >> 2) << 3) + (khalf << 2);
            fsmem[(wr * 32 + rl) * 129 + (wcp * 2 + cq) * 32 + lrow] = acc[cq][i];
        }
    __syncthreads();
    const int rloc = tid & 127;
    const int r = rowBase + rloc;
    #pragma unroll
    for (int gi = 0; gi < 4; ++gi) {
        int g = (tid >> 7) + gi * 4;
        int c0 = colBase + g * 8;
        int so = swoff(r, c0);
        float v[8];
        #pragma unroll
        for (int j = 0; j < 8; ++j) v[j] = fsmem[rloc * 129 + g * 8 + j];
        ushort8 mh = *(const ushort8*)(Mh + mb + so);
        ushort8 mlv = *(const ushort8*)(Ml + mb + so);
        if (MODE == 2) {
            int tb = r * CD - (r * (r - 1)) / 2 - r;
            #pragma unroll
            for (int j = 0; j < 8; ++j) {
                float m = bf2f(mh[j]) + bf2f(mlv[j]);
                float y = fmaf(1.5f, m, -0.5f * v[j]);
                int c = c0 + j;
                if (c >= r) outT[(size_t)bbx * TRIU_N + tb + c] = st * y;
            }
        } else {
            ushort8 hh, ll;
            #pragma unroll
            for (int j = 0; j < 8; ++j) {
                float m = bf2f(mh[j]) + bf2f(mlv[j]);
                float y;
                if (MODE == 1) y = it * fmaf(1.5f, m, -0.5f * it * v[j]);
                else           y = fmaf(1.5f, m, -0.5f * v[j]);
                ushort_t h, l; split2(y, h, l);
                hh[j] = h; ll[j] = l;
            }
            *(ushort8*)(O1h + mb + so) = hh;
            *(ushort8*)(O1l + mb + so) = ll;
        }
    }
}

// ---------------------------------------------------------------------------
// Fused everything: gram(+means+trace) then 6 NS GEMMs, per-batch spin sync.
__global__ __launch_bounds__(512, 1)
void covns_k(const float* __restrict__ X, float* __restrict__ tr, int* __restrict__ cnt,
             ushort_t* S0h, ushort_t* S0l, ushort_t* S1h, ushort_t* S1l,
             ushort_t* S2h, ushort_t* S2l, ushort_t* S3h, ushort_t* S3l,
             float* __restrict__ out) {
    __shared__ __align__(16) float fsmem[16512];   // 66 KB staging / bounce
    __shared__ float smean[256];
    __shared__ float s_tr[2];
    ushort_t* us = (ushort_t*)fsmem;

    const int bid = blockIdx.x;
    const int bbx = bid & 63;          // batch  (tiles of a batch ≡ b mod 8 -> same XCD)
    const int tile = bid >> 6;         // 0..3
    const int rowBase = (tile >> 1) * 128, colBase = (tile & 1) * 128;
    const int tid = threadIdx.x, lane = tid & 63, wv = tid >> 6;
    const int wr = wv >> 1, wcp = wv & 1;
    const int khalf = lane >> 5, lrow = lane & 31;
    const float* Xb = X + (size_t)bbx * CD * NX;
    const size_t mb = (size_t)bbx * MSZ;
    int* mycnt = cnt + bbx;

    // ------------------- Phase 1: Gram + means + trace -------------------
    const int srow = (tid >> 2) & 127;
    const int skq  = tid & 3;

    floatx16 acc[2];
    #pragma unroll
    for (int cq = 0; cq < 2; ++cq)
        #pragma unroll
        for (int i = 0; i < 16; ++i) acc[cq][i] = 0.f;

    float msum[2] = {0.f, 0.f};
    float4 cur[2][2][2];   // [parity][side][half]

    auto loadst = [&](int s, int d) {
        int gk = s * 32 + skq * 8;
        if (gk < NX) {
            const float* pa = Xb + (size_t)(rowBase + srow) * NX + gk;
            const float* pb = Xb + (size_t)(colBase + srow) * NX + gk;
            cur[d][0][0] = *(const float4*)pa; cur[d][0][1] = *(const float4*)(pa + 4);
            cur[d][1][0] = *(const float4*)pb; cur[d][1][1] = *(const float4*)(pb + 4);
        } else {
            float4 z = make_float4(0.f, 0.f, 0.f, 0.f);
            cur[d][0][0] = z; cur[d][0][1] = z; cur[d][1][0] = z; cur[d][1][1] = z;
        }
    };
    auto splitwr = [&](int d) {
        #pragma unroll
        for (int side = 0; side < 2; ++side) {
            float f[8] = {cur[d][side][0].x, cur[d][side][0].y, cur[d][side][0].z, cur[d][side][0].w,
                          cur[d][side][1].x, cur[d][side][1].y, cur[d][side][1].z, cur[d][side][1].w};
            msum[side] += ((f[0]+f[1])+(f[2]+f[3])) + ((f[4]+f[5])+(f[6]+f[7]));
            uint_t hp[4], lp[4];
            #pragma unroll
            for (int i = 0; i < 4; ++i) {
                ushort_t h0, l0, h1, l1;
                split2(f[2*i], h0, l0); split2(f[2*i+1], h1, l1);
                hp[i] = (uint_t)h0 | ((uint_t)h1 << 16);
                lp[i] = (uint_t)l0 | ((uint_t)l1 << 16);
            }
            int base = d * BUF_STRIDE + (side * 2) * ARR_STRIDE + skq * REG_STRIDE + srow * 8;
            *(uint4*)(us + base)              = make_uint4(hp[0], hp[1], hp[2], hp[3]);
            *(uint4*)(us + base + ARR_STRIDE) = make_uint4(lp[0], lp[1], lp[2], lp[3]);
        }
    };
    auto gram_iter = [&](int s, int par) {
        __syncthreads();
        if (s + 2 <= 24) loadst(s + 2, par);
        if (s + 1 <= 24) splitwr(par ^ 1);
        mfma_stage8(us, par * BUF_STRIDE, wr, wcp, khalf, lrow, acc);
    };

    loadst(0, 0);
    splitwr(0);
    loadst(1, 1);
    for (int s = 0; s < 24; s += 2) { gram_iter(s, 0); gram_iter(s + 1, 1); }
    gram_iter(24, 0);

    // means reduce (row panel -> smean[0..127], col panel -> smean[128..255])
    __syncthreads();
    fsmem[srow * 4 + skq]         = msum[0];
    fsmem[(128 + srow) * 4 + skq] = msum[1];
    __syncthreads();
    if (tid < 256)
        smean[tid] = (fsmem[tid*4] + fsmem[tid*4+1] + fsmem[tid*4+2] + fsmem[tid*4+3]) * (1.0f / NX);
    __syncthreads();

    // Sigma epilogue via LDS bounce + diag trace
    #pragma unroll
    for (int cq = 0; cq < 2; ++cq)
        #pragma unroll
        for (int i = 0; i < 16; ++i) {
            int rl = (i & 3) + ((i >> 2) << 3) + (khalf << 2);
            fsmem[(wr * 32 + rl) * 129 + (wcp * 2 + cq) * 32 + lrow] = acc[cq][i];
        }
    __syncthreads();
    {
        const int rloc = tid & 127;
        const int r = rowBase + rloc;
        const float mr = smean[rloc];
        float tsum = 0.f;
        #pragma unroll
        for (int gi = 0; gi < 4; ++gi) {
            int g = (tid >> 7) + gi * 4;
            int c0 = colBase + g * 8;
            int so = swoff(r, c0);
            ushort8 hh, ll;
            #pragma unroll
            for (int j = 0; j < 8; ++j) {
                float v = fsmem[rloc * 129 + g * 8 + j] * (1.0f / NX) - mr * smean[128 + g * 8 + j];
                if (rowBase == colBase && (g * 8 + j) == rloc) tsum += v;
                ushort_t h, l; split2(v, h, l);
                hh[j] = h; ll[j] = l;
            }
            *(ushort8*)(S0h + mb + so) = hh;
            *(ushort8*)(S0l + mb + so) = ll;
        }
        if (rowBase == colBase) {
            for (int off = 32; off; off >>= 1) tsum += __shfl_down(tsum, off, 64);
            if (lane == 0) atomicAdd(&tr[bbx], tsum);
        }
    }

    batch_sync(mycnt, 4, tid);
    if (tid == 0) {
        float t = __hip_atomic_load(&tr[bbx], __ATOMIC_RELAXED, __HIP_MEMORY_SCOPE_AGENT);
        s_tr[0] = 1.0f / t;
        s_tr[1] = sqrtf(t);
    }
    __syncthreads();
    const float it = s_tr[0], st = s_tr[1];

    // ------------------- Phase 2: 6-GEMM NS chain -------------------
    // s0: Y1 = it*(1.5*Sig - 0.5*it*Sig^2)   [S0 -> S1], M = Sig
    ns_step<1>(fsmem, S0h, S0l, S0h, S0l, S0h, S0l, S1h, S1l, nullptr, it, 0.f,
               rowBase, colBase, mb, bbx, tid, lane, wv, wr, wcp, khalf, lrow);
    batch_sync(mycnt, 8, tid);
    // s1: T1 = 1.5*Y1 - 0.5*Y1^2             [S1 -> S2], M = Y1
    ns_step<0>(fsmem, S1h, S1l, S1h, S1l, S1h, S1l, S2h, S2l, nullptr, 0.f, 0.f,
               rowBase, colBase, mb, bbx, tid, lane, wv, wr, wcp, khalf, lrow);
    batch_sync(mycnt, 12, tid);
    // s2: Y2 = 1.5*Y1 - 0.5*(Y1*T1)          [S1,S2 -> S3], M = Y1
    ns_step<0>(fsmem, S1h, S1l, S2h, S2l, S1h, S1l, S3h, S3l, nullptr, 0.f, 0.f,
               rowBase, colBase, mb, bbx, tid, lane, wv, wr, wcp, khalf, lrow);
    batch_sync(mycnt, 16, tid);
    // s3: T2 = 1.5*Y2 - 0.5*(Y1*Y2)          [S1,S3 -> S0], M = Y2
    ns_step<0>(fsmem, S1h, S1l, S3h, S3l, S3h, S3l, S0h, S0l, nullptr, 0.f, 0.f,
               rowBase, colBase, mb, bbx, tid, lane, wv, wr, wcp, khalf, lrow);
    batch_sync(mycnt, 20, tid);
    // s4: T3 = 1.5*T2 - 0.5*T2^2             [S0 -> S2], M = T2
    ns_step<0>(fsmem, S0h, S0l, S0h, S0l, S0h, S0l, S2h, S2l, nullptr, 0.f, 0.f,
               rowBase, colBase, mb, bbx, tid, lane, wv, wr, wcp, khalf, lrow);
    batch_sync(mycnt, 24, tid);
    // s5: out = st*(1.5*Y2 - 0.5*(Y2*T3)), triu  [S3,S2 -> out], M = Y2
    if (!(rowBase > colBase))
        ns_step<2>(fsmem, S3h, S3l, S2h, S2l, S3h, S3l, nullptr, nullptr, out, 0.f, st,
                   rowBase, colBase, mb, bbx, tid, lane, wv, wr, wcp, khalf, lrow);
}

// ---------------------------------------------------------------------------
extern "C" void kernel_launch(void* const* d_in, const int* in_sizes, int n_in,
                              void* d_out, int out_size, void* d_ws, size_t ws_size,
                              hipStream_t stream) {
    const float* x = (const float*)d_in[0];
    float* out = (float*)d_out;
    char* ws = (char*)d_ws;
    const size_t HS = (size_t)BATCH * MSZ * 2;   // 8 MB per half-matrix array
    ushort_t* S0h = (ushort_t*)(ws + 0 * HS);
    ushort_t* S0l = (ushort_t*)(ws + 1 * HS);
    ushort_t* S1h = (ushort_t*)(ws + 2 * HS);
    ushort_t* S1l = (ushort_t*)(ws + 3 * HS);
    ushort_t* S2h = (ushort_t*)(ws + 4 * HS);
    ushort_t* S2l = (ushort_t*)(ws + 5 * HS);
    ushort_t* S3h = (ushort_t*)(ws + 6 * HS);
    ushort_t* S3l = (ushort_t*)(ws + 7 * HS);
    float* tr = (float*)(ws + 8 * HS);           // 64 floats
    int* cnt = (int*)(tr + BATCH);               // 64 ints

    hipMemsetAsync(tr, 0, BATCH * (sizeof(float) + sizeof(int)), stream);
    covns_k<<<256, 512, 0, stream>>>(x, tr, cnt, S0h, S0l, S1h, S1l,
                                     S2h, S2l, S3h, S3l, out);
}